// Round 4
// baseline (339.676 us; speedup 1.0000x reference)
//
#include <hip/hip_runtime.h>

using u16 = unsigned short;
using u32 = unsigned int;

// Problem constants: B=8, T=2048, C=1024
constexpr int Cdim  = 1024;
constexpr int Bn    = 8;
constexpr int Tn    = 2048;
constexpr int Mrows = Bn * Tn;          // 16384 rows in all GEMMs
constexpr int NCH   = 32;               // wkv chunks per chain
constexpr int CLEN  = Tn / NCH;         // 64 steps per chunk

// ---------- bf16 helpers (bit-level, RNE) ----------
__device__ inline u16 f2bf(float x) {
    u32 u = __float_as_uint(x);
    u += 0x7fffu + ((u >> 16) & 1u);
    return (u16)(u >> 16);
}
__device__ inline float bf2f_lo(u32 u) { return __uint_as_float(u << 16); }
__device__ inline float bf2f_hi(u32 u) { return __uint_as_float(u & 0xFFFF0000u); }

// ---------- merged cast: X + 3 weight matrices, ONE dispatch ----------
constexpr int XB = (Mrows * Cdim / 4) / 256;   // 16384 blocks for X
constexpr int WB = (Cdim * Cdim / 4) / 256;    // 1024 blocks per weight

__global__ __launch_bounds__(256)
void cast_all(const float* __restrict__ x,  const float* __restrict__ wv,
              const float* __restrict__ wr, const float* __restrict__ wo,
              u16* __restrict__ xb, u16* __restrict__ wvb,
              u16* __restrict__ wrb, u16* __restrict__ wob)
{
    const int blk = blockIdx.x;
    const float* in; u16* out; int i;
    if (blk < XB)              { in = x;  out = xb;  i = blk; }
    else if (blk < XB + WB)    { in = wv; out = wvb; i = blk - XB; }
    else if (blk < XB + 2*WB)  { in = wr; out = wrb; i = blk - XB - WB; }
    else                       { in = wo; out = wob; i = blk - XB - 2*WB; }
    const int e = i * 256 + threadIdx.x;
    float4 v = ((const float4*)in)[e];
    ushort4 o;
    o.x = f2bf(v.x); o.y = f2bf(v.y); o.z = f2bf(v.z); o.w = f2bf(v.w);
    ((ushort4*)out)[e] = o;
}

// ---------- MFMA bf16 NT-GEMM common bits ----------
typedef __bf16 bf16x8 __attribute__((ext_vector_type(8)));
typedef float  f32x16 __attribute__((ext_vector_type(16)));

__device__ inline void load_lds16(const void* g, void* l) {
    __builtin_amdgcn_global_load_lds(
        (const __attribute__((address_space(1))) void*)g,
        (__attribute__((address_space(3))) void*)l, 16, 0, 0);
}

// XCD-aware swizzle: XCD (L&7) owns m-tiles [16k,16k+16); the 8 n-tiles of
// one m-tile run consecutively so the A-tile stays hot in that XCD's L2.
__device__ inline void swizzle_tiles(int& mt, int& nt) {
    const int L   = blockIdx.y * gridDim.x + blockIdx.x;  // 0..1023
    const int xcd = L & 7;
    const int s   = L >> 3;          // 0..127
    mt = xcd * 16 + (s >> 3);        // 0..127
    nt = s & 7;                      // 0..7
}

// ---------- Dual-output GEMM: V = A@Wv^T, R = sigmoid(A@Wr^T) ----------
// 128x128 tile, BK=32, 4 waves in 2x2, each wave 64x64 per output via
// 2x2 of 32x32x16 MFMA (2 k-steps per BK).
__global__ __launch_bounds__(256, 2)
void gemm_dual(const u16* __restrict__ A, const u16* __restrict__ Wv,
               const u16* __restrict__ Wr, u16* __restrict__ Vb, u16* __restrict__ Rb)
{
    __shared__ alignas(16) u16 As[128 * 32];
    __shared__ alignas(16) u16 Bv[128 * 32];
    __shared__ alignas(16) u16 Br[128 * 32];

    const int tid  = threadIdx.x;
    const int wave = tid >> 6;
    const int lane = tid & 63;

    int mt, nt;
    swizzle_tiles(mt, nt);
    const int m0 = mt * 128;
    const int n0 = nt * 128;

    const int wr = wave >> 1;        // wave row-half
    const int wc = wave & 1;         // wave col-half

    const int srow = (lane >> 2);
    const int scol = (lane & 3) * 8;

    // fragment addressing (32x32x16): row/col = lane&31, k = (lane>>5)*8
    const int fr  = lane & 31;
    const int fkh = (lane >> 5) * 8;

    f32x16 accV[2][2] = {};
    f32x16 accR[2][2] = {};

    for (int kt = 0; kt < Cdim; kt += 32) {
        #pragma unroll
        for (int p = 0; p < 2; ++p) {
            const int row = wave * 32 + p * 16 + srow;
            const int lo  = wave * 2048 + p * 1024;
            load_lds16(A  + (size_t)(m0 + row) * Cdim + kt + scol, (char*)As + lo);
            load_lds16(Wv + (size_t)(n0 + row) * Cdim + kt + scol, (char*)Bv + lo);
            load_lds16(Wr + (size_t)(n0 + row) * Cdim + kt + scol, (char*)Br + lo);
        }
        __syncthreads();

        bf16x8 af[2][2], bv[2][2], br[2][2];   // [sub][ks]
        #pragma unroll
        for (int ms = 0; ms < 2; ++ms)
            #pragma unroll
            for (int ks = 0; ks < 2; ++ks) {
                const int ai = (wr * 64 + ms * 32 + fr) * 32 + ks * 16 + fkh;
                const int bi = (wc * 64 + ms * 32 + fr) * 32 + ks * 16 + fkh;
                af[ms][ks] = *(const bf16x8*)&As[ai];
                bv[ms][ks] = *(const bf16x8*)&Bv[bi];
                br[ms][ks] = *(const bf16x8*)&Br[bi];
            }
        #pragma unroll
        for (int ms = 0; ms < 2; ++ms)
            #pragma unroll
            for (int ns = 0; ns < 2; ++ns)
                #pragma unroll
                for (int ks = 0; ks < 2; ++ks) {
                    accV[ms][ns] = __builtin_amdgcn_mfma_f32_32x32x16_bf16(af[ms][ks], bv[ns][ks], accV[ms][ns], 0, 0, 0);
                    accR[ms][ns] = __builtin_amdgcn_mfma_f32_32x32x16_bf16(af[ms][ks], br[ns][ks], accR[ms][ns], 0, 0, 0);
                }
        __syncthreads();
    }

    // C/D layout (32x32): col = lane&31, row = (r&3) + 8*(r>>2) + 4*(lane>>5)
    #pragma unroll
    for (int ms = 0; ms < 2; ++ms)
        #pragma unroll
        for (int ns = 0; ns < 2; ++ns) {
            const int col   = n0 + wc * 64 + ns * 32 + (lane & 31);
            const int rbase = m0 + wr * 64 + ms * 32 + 4 * (lane >> 5);
            #pragma unroll
            for (int r = 0; r < 16; ++r) {
                const int row = rbase + (r & 3) + 8 * (r >> 2);
                const size_t o = (size_t)row * Cdim + col;
                Vb[o] = f2bf(accV[ms][ns][r]);
                const float rv = accR[ms][ns][r];
                Rb[o] = f2bf(1.f / (1.f + __expf(-rv)));
            }
        }
}

// ---------- Single GEMM: out = Y @ Wo^T (fp32 out) ----------
__global__ __launch_bounds__(256, 3)
void gemm_single(const u16* __restrict__ A, const u16* __restrict__ W, float* __restrict__ O)
{
    __shared__ alignas(16) u16 As[128 * 32];
    __shared__ alignas(16) u16 Bs[128 * 32];

    const int tid  = threadIdx.x;
    const int wave = tid >> 6;
    const int lane = tid & 63;

    int mt, nt;
    swizzle_tiles(mt, nt);
    const int m0 = mt * 128;
    const int n0 = nt * 128;

    const int wr = wave >> 1;
    const int wc = wave & 1;

    const int srow = (lane >> 2);
    const int scol = (lane & 3) * 8;

    const int fr  = lane & 31;
    const int fkh = (lane >> 5) * 8;

    f32x16 acc[2][2] = {};

    for (int kt = 0; kt < Cdim; kt += 32) {
        #pragma unroll
        for (int p = 0; p < 2; ++p) {
            const int row = wave * 32 + p * 16 + srow;
            const int lo  = wave * 2048 + p * 1024;
            load_lds16(A + (size_t)(m0 + row) * Cdim + kt + scol, (char*)As + lo);
            load_lds16(W + (size_t)(n0 + row) * Cdim + kt + scol, (char*)Bs + lo);
        }
        __syncthreads();

        bf16x8 af[2][2], bf_[2][2];
        #pragma unroll
        for (int ms = 0; ms < 2; ++ms)
            #pragma unroll
            for (int ks = 0; ks < 2; ++ks) {
                af[ms][ks]  = *(const bf16x8*)&As[(wr * 64 + ms * 32 + fr) * 32 + ks * 16 + fkh];
                bf_[ms][ks] = *(const bf16x8*)&Bs[(wc * 64 + ms * 32 + fr) * 32 + ks * 16 + fkh];
            }
        #pragma unroll
        for (int ms = 0; ms < 2; ++ms)
            #pragma unroll
            for (int ns = 0; ns < 2; ++ns)
                #pragma unroll
                for (int ks = 0; ks < 2; ++ks)
                    acc[ms][ns] = __builtin_amdgcn_mfma_f32_32x32x16_bf16(af[ms][ks], bf_[ns][ks], acc[ms][ns], 0, 0, 0);
        __syncthreads();
    }

    #pragma unroll
    for (int ms = 0; ms < 2; ++ms)
        #pragma unroll
        for (int ns = 0; ns < 2; ++ns) {
            const int col   = n0 + wc * 64 + ns * 32 + (lane & 31);
            const int rbase = m0 + wr * 64 + ms * 32 + 4 * (lane >> 5);
            #pragma unroll
            for (int r = 0; r < 16; ++r) {
                const int row = rbase + (r & 3) + 8 * (r >> 2);
                O[(size_t)row * Cdim + col] = acc[ms][ns][r];
            }
        }
}

// ---------- WKV: constant-coefficient linear recurrence, chunk-parallel ----------
// Vectorized x8: each thread owns 8 consecutive channels (16B loads/stores).
// pass1: per-chunk decayed partial sums Sa. pass2: prefix-combine + replay.
__global__ __launch_bounds__(256)
void wkv_pass1(const u16* __restrict__ Vb, const float* __restrict__ td,
               float* __restrict__ Sa)
{
    const int t     = blockIdx.x * 256 + threadIdx.x;   // 0..32767
    const int cg    = t & 127;
    const int chunk = (t >> 7) & (NCH - 1);
    const int b     = t >> 12;
    const int c0    = cg * 8;

    const float4 t0 = *(const float4*)&td[c0];
    const float4 t1 = *(const float4*)&td[c0 + 4];
    const float tdv[8] = {t0.x, t0.y, t0.z, t0.w, t1.x, t1.y, t1.z, t1.w};
    float lam[8], mu[8];
    #pragma unroll
    for (int j = 0; j < 8; ++j) {
        lam[j] = __expf(-fmaxf(tdv[j], 0.f));
        mu[j]  = __expf(fminf(tdv[j], 0.f));
    }

    float s[8] = {};
    size_t idx = ((size_t)(b * Tn + chunk * CLEN)) * Cdim + c0;
    for (int i = 0; i < CLEN; ++i, idx += Cdim) {
        const uint4 pv = *(const uint4*)&Vb[idx];
        const u32 w[4] = {pv.x, pv.y, pv.z, pv.w};
        #pragma unroll
        for (int q = 0; q < 4; ++q) {
            s[2*q]   = lam[2*q]   * s[2*q]   + mu[2*q]   * bf2f_lo(w[q]);
            s[2*q+1] = lam[2*q+1] * s[2*q+1] + mu[2*q+1] * bf2f_hi(w[q]);
        }
    }
    float* dst = &Sa[((size_t)b * NCH + chunk) * Cdim + c0];
    *(float4*)dst       = make_float4(s[0], s[1], s[2], s[3]);
    *(float4*)(dst + 4) = make_float4(s[4], s[5], s[6], s[7]);
}

__global__ __launch_bounds__(256)
void wkv_pass2(const u16* __restrict__ Vb, const u16* __restrict__ Rb,
               const float* __restrict__ td, const float* __restrict__ tf,
               const float* __restrict__ Sa, u16* __restrict__ Y)
{
    const int t     = blockIdx.x * 256 + threadIdx.x;
    const int cg    = t & 127;
    const int chunk = (t >> 7) & (NCH - 1);
    const int b     = t >> 12;
    const int c0    = cg * 8;

    const float4 t0 = *(const float4*)&td[c0];
    const float4 t1 = *(const float4*)&td[c0 + 4];
    const float4 f0 = *(const float4*)&tf[c0];
    const float4 f1 = *(const float4*)&tf[c0 + 4];
    const float tdv[8] = {t0.x, t0.y, t0.z, t0.w, t1.x, t1.y, t1.z, t1.w};
    const float tfv[8] = {f0.x, f0.y, f0.z, f0.w, f1.x, f1.y, f1.z, f1.w};

    float lam[8], mu[8], e1[8], e2[8], lamL[8], Sb[8];
    #pragma unroll
    for (int j = 0; j < 8; ++j) {
        const float mx = fmaxf(tdv[j], 0.f);
        lam[j]  = __expf(-mx);
        mu[j]   = __expf(fminf(tdv[j], 0.f));
        e1[j]   = __expf(-fmaxf(tfv[j], 0.f));
        e2[j]   = __expf(fminf(tfv[j], 0.f));
        lamL[j] = __expf(-(float)CLEN * mx);
        Sb[j]   = (fabsf(1.f - lam[j]) < 1e-9f) ? mu[j] * (float)CLEN
                                                : mu[j] * (1.f - lamL[j]) / (1.f - lam[j]);
    }

    float aa[8] = {}, bb[8] = {};
    for (int jj = 0; jj < chunk; ++jj) {            // chunk is wave-uniform
        const float* sp = &Sa[((size_t)b * NCH + jj) * Cdim + c0];
        const float4 s0 = *(const float4*)sp;
        const float4 s1 = *(const float4*)(sp + 4);
        const float sv[8] = {s0.x, s0.y, s0.z, s0.w, s1.x, s1.y, s1.z, s1.w};
        #pragma unroll
        for (int j = 0; j < 8; ++j) {
            aa[j] = lamL[j] * aa[j] + sv[j];
            bb[j] = lamL[j] * bb[j] + Sb[j];
        }
    }

    size_t idx = ((size_t)(b * Tn + chunk * CLEN)) * Cdim + c0;
    for (int i = 0; i < CLEN; ++i, idx += Cdim) {
        const uint4 pv = *(const uint4*)&Vb[idx];
        const uint4 pr = *(const uint4*)&Rb[idx];
        const u32 vw[4] = {pv.x, pv.y, pv.z, pv.w};
        const u32 rw[4] = {pr.x, pr.y, pr.z, pr.w};
        u32 ow[4];
        #pragma unroll
        for (int q = 0; q < 4; ++q) {
            const int j0 = 2 * q, j1 = 2 * q + 1;
            const float v0 = bf2f_lo(vw[q]), v1 = bf2f_hi(vw[q]);
            const float r0 = bf2f_lo(rw[q]), r1 = bf2f_hi(rw[q]);
            const float k0 = (e1[j0] * aa[j0] + e2[j0] * v0) / (e1[j0] * bb[j0] + e2[j0] + 1e-6f);
            const float k1 = (e1[j1] * aa[j1] + e2[j1] * v1) / (e1[j1] * bb[j1] + e2[j1] + 1e-6f);
            ow[q] = (u32)f2bf(r0 * k0) | ((u32)f2bf(r1 * k1) << 16);
            aa[j0] = lam[j0] * aa[j0] + mu[j0] * v0;
            aa[j1] = lam[j1] * aa[j1] + mu[j1] * v1;
            bb[j0] = lam[j0] * bb[j0] + mu[j0];
            bb[j1] = lam[j1] * bb[j1] + mu[j1];
        }
        *(uint4*)&Y[idx] = make_uint4(ow[0], ow[1], ow[2], ow[3]);
    }
}

extern "C" void kernel_launch(void* const* d_in, const int* in_sizes, int n_in,
                              void* d_out, int out_size, void* d_ws, size_t ws_size,
                              hipStream_t stream)
{
    // inputs: x, time_decay, time_first, key_w(dead), value_w, recep_w, out_w
    const float* x       = (const float*)d_in[0];
    const float* td      = (const float*)d_in[1];
    const float* tf      = (const float*)d_in[2];
    const float* value_w = (const float*)d_in[4];
    const float* recep_w = (const float*)d_in[5];
    const float* out_w   = (const float*)d_in[6];
    float* out = (float*)d_out;

    char* ws = (char*)d_ws;
    const size_t MB = 1024 * 1024;
    u16*   Xb = (u16*)(ws);               // 32 MB; reused as Yb after dual GEMM
    u16*   Vb = (u16*)(ws + 32 * MB);     // 32 MB
    u16*   Rb = (u16*)(ws + 64 * MB);     // 32 MB
    u16*   Wv = (u16*)(ws + 96 * MB);     //  2 MB
    u16*   Wr = (u16*)(ws + 98 * MB);     //  2 MB
    u16*   Wo = (u16*)(ws + 100 * MB);    //  2 MB
    float* Sa = (float*)(ws + 102 * MB);  //  1 MB [8][32][1024]
    u16*   Yb = Xb;                       // alias: Xb dead after dual GEMM

    cast_all<<<XB + 3 * WB, 256, 0, stream>>>(x, value_w, recep_w, out_w, Xb, Wv, Wr, Wo);

    dim3 ggrid(Cdim / 128, Mrows / 128);  // (8, 128) -> 1024 blocks
    gemm_dual<<<ggrid, 256, 0, stream>>>(Xb, Wv, Wr, Vb, Rb);

    const int nScan = Bn * NCH * (Cdim / 8);   // 32768 threads
    wkv_pass1<<<nScan / 256, 256, 0, stream>>>(Vb, td, Sa);
    wkv_pass2<<<nScan / 256, 256, 0, stream>>>(Vb, Rb, td, tf, Sa, Yb);

    gemm_single<<<ggrid, 256, 0, stream>>>(Yb, Wo, out);
}

// Round 5
// 324.611 us; speedup vs baseline: 1.0464x; 1.0464x over previous
//
#include <hip/hip_runtime.h>

using u16 = unsigned short;
using u32 = unsigned int;

// Problem constants: B=8, T=2048, C=1024
constexpr int Cdim  = 1024;
constexpr int Bn    = 8;
constexpr int Tn    = 2048;
constexpr int Mrows = Bn * Tn;          // 16384 rows in all GEMMs
constexpr int NCH   = 32;               // wkv chunks per chain
constexpr int CLEN  = Tn / NCH;         // 64 steps per chunk

// ---------- bf16 helpers (bit-level, RNE) ----------
__device__ inline u16 f2bf(float x) {
    u32 u = __float_as_uint(x);
    u += 0x7fffu + ((u >> 16) & 1u);
    return (u16)(u >> 16);
}
__device__ inline float bf2f_lo(u32 u) { return __uint_as_float(u << 16); }
__device__ inline float bf2f_hi(u32 u) { return __uint_as_float(u & 0xFFFF0000u); }

// ---------- merged cast: X + 3 weight matrices, ONE dispatch ----------
constexpr int XB = (Mrows * Cdim / 4) / 256;   // 16384 blocks for X
constexpr int WB = (Cdim * Cdim / 4) / 256;    // 1024 blocks per weight

__global__ __launch_bounds__(256)
void cast_all(const float* __restrict__ x,  const float* __restrict__ wv,
              const float* __restrict__ wr, const float* __restrict__ wo,
              u16* __restrict__ xb, u16* __restrict__ wvb,
              u16* __restrict__ wrb, u16* __restrict__ wob)
{
    const int blk = blockIdx.x;
    const float* in; u16* out; int i;
    if (blk < XB)              { in = x;  out = xb;  i = blk; }
    else if (blk < XB + WB)    { in = wv; out = wvb; i = blk - XB; }
    else if (blk < XB + 2*WB)  { in = wr; out = wrb; i = blk - XB - WB; }
    else                       { in = wo; out = wob; i = blk - XB - 2*WB; }
    const int e = i * 256 + threadIdx.x;
    float4 v = ((const float4*)in)[e];
    ushort4 o;
    o.x = f2bf(v.x); o.y = f2bf(v.y); o.z = f2bf(v.z); o.w = f2bf(v.w);
    ((ushort4*)out)[e] = o;
}

// ---------- MFMA bf16 NT-GEMM common bits (16x16x32 fragments) ----------
typedef __bf16 bf16x8 __attribute__((ext_vector_type(8)));
typedef float  f32x4  __attribute__((ext_vector_type(4)));

__device__ inline void load_lds16(const void* g, void* l) {
    __builtin_amdgcn_global_load_lds(
        (const __attribute__((address_space(1))) void*)g,
        (__attribute__((address_space(3))) void*)l, 16, 0, 0);
}

// XCD-aware swizzle: XCD (L&7) owns m-tiles [16k,16k+16); the 8 n-tiles of
// one m-tile run consecutively so the A-tile stays hot in that XCD's L2.
__device__ inline void swizzle_tiles(int& mt, int& nt) {
    const int L   = blockIdx.y * gridDim.x + blockIdx.x;  // 0..1023
    const int xcd = L & 7;
    const int s   = L >> 3;          // 0..127
    mt = xcd * 16 + (s >> 3);        // 0..127
    nt = s & 7;                      // 0..7
}

// ---------- Dual-output GEMM: V = A@Wv^T, R = sigmoid(A@Wr^T) ----------
// 128x128 tile, BK=32, 4 waves 2x2, each wave 4x4 of 16x16x32 MFMA per output.
__global__ __launch_bounds__(256, 2)
void gemm_dual(const u16* __restrict__ A, const u16* __restrict__ Wv,
               const u16* __restrict__ Wr, u16* __restrict__ Vb, u16* __restrict__ Rb)
{
    __shared__ alignas(16) u16 As[128 * 32];
    __shared__ alignas(16) u16 Bv[128 * 32];
    __shared__ alignas(16) u16 Br[128 * 32];

    const int tid  = threadIdx.x;
    const int wave = tid >> 6;
    const int lane = tid & 63;

    int mt, nt;
    swizzle_tiles(mt, nt);
    const int m0 = mt * 128;
    const int n0 = nt * 128;

    const int wr = wave >> 1;
    const int wc = wave & 1;

    const int srow = (lane >> 2);
    const int scol = (lane & 3) * 8;

    f32x4 accV[4][4] = {};
    f32x4 accR[4][4] = {};

    for (int kt = 0; kt < Cdim; kt += 32) {
        #pragma unroll
        for (int p = 0; p < 2; ++p) {
            const int row = wave * 32 + p * 16 + srow;
            const int lo  = wave * 2048 + p * 1024;
            load_lds16(A  + (size_t)(m0 + row) * Cdim + kt + scol, (char*)As + lo);
            load_lds16(Wv + (size_t)(n0 + row) * Cdim + kt + scol, (char*)Bv + lo);
            load_lds16(Wr + (size_t)(n0 + row) * Cdim + kt + scol, (char*)Br + lo);
        }
        __syncthreads();

        bf16x8 af[4], bv[4], br[4];
        #pragma unroll
        for (int i = 0; i < 4; ++i) {
            const int ai = (wr * 64 + i * 16 + (lane & 15)) * 32 + (lane >> 4) * 8;
            const int bi = (wc * 64 + i * 16 + (lane & 15)) * 32 + (lane >> 4) * 8;
            af[i] = *(const bf16x8*)&As[ai];
            bv[i] = *(const bf16x8*)&Bv[bi];
            br[i] = *(const bf16x8*)&Br[bi];
        }
        #pragma unroll
        for (int i = 0; i < 4; ++i)
            #pragma unroll
            for (int j = 0; j < 4; ++j) {
                accV[i][j] = __builtin_amdgcn_mfma_f32_16x16x32_bf16(af[i], bv[j], accV[i][j], 0, 0, 0);
                accR[i][j] = __builtin_amdgcn_mfma_f32_16x16x32_bf16(af[i], br[j], accR[i][j], 0, 0, 0);
            }
        __syncthreads();
    }

    const int col0 = n0 + wc * 64 + (lane & 15);
    const int row0 = m0 + wr * 64 + (lane >> 4) * 4;
    #pragma unroll
    for (int i = 0; i < 4; ++i)
        #pragma unroll
        for (int j = 0; j < 4; ++j) {
            const int col = col0 + j * 16;
            #pragma unroll
            for (int r = 0; r < 4; ++r) {
                const size_t o = (size_t)(row0 + i * 16 + r) * Cdim + col;
                Vb[o] = f2bf(accV[i][j][r]);
                const float rv = accR[i][j][r];
                Rb[o] = f2bf(1.f / (1.f + __expf(-rv)));
            }
        }
}

// ---------- Single GEMM, 2 m-tiles per block sharing W: out = Y @ Wo^T ----------
// 256x128 effective tile, 3 LDS slabs, 32 MFMA per K-iter (same density as dual).
__global__ __launch_bounds__(256, 2)
void gemm_single2(const u16* __restrict__ A, const u16* __restrict__ W, float* __restrict__ O)
{
    __shared__ alignas(16) u16 A0[128 * 32];
    __shared__ alignas(16) u16 A1[128 * 32];
    __shared__ alignas(16) u16 Bs[128 * 32];

    const int tid  = threadIdx.x;
    const int wave = tid >> 6;
    const int lane = tid & 63;

    // swizzle over 512 blocks: XCD (L&7) owns mt2 range [8k,8k+8)
    const int L   = blockIdx.x;          // 0..511
    const int xcd = L & 7;
    const int s   = L >> 3;              // 0..63
    const int mt2 = xcd * 8 + (s >> 3);  // 0..63
    const int nt  = s & 7;
    const int m0  = mt2 * 256;
    const int n0  = nt * 128;

    const int wr = wave >> 1;
    const int wc = wave & 1;

    const int srow = (lane >> 2);
    const int scol = (lane & 3) * 8;

    f32x4 acc0[4][4] = {};
    f32x4 acc1[4][4] = {};

    for (int kt = 0; kt < Cdim; kt += 32) {
        #pragma unroll
        for (int p = 0; p < 2; ++p) {
            const int row = wave * 32 + p * 16 + srow;
            const int lo  = wave * 2048 + p * 1024;
            load_lds16(A + (size_t)(m0 + row) * Cdim + kt + scol,       (char*)A0 + lo);
            load_lds16(A + (size_t)(m0 + 128 + row) * Cdim + kt + scol, (char*)A1 + lo);
            load_lds16(W + (size_t)(n0 + row) * Cdim + kt + scol,       (char*)Bs + lo);
        }
        __syncthreads();

        bf16x8 af0[4], af1[4], bf_[4];
        #pragma unroll
        for (int i = 0; i < 4; ++i) {
            const int ai = (wr * 64 + i * 16 + (lane & 15)) * 32 + (lane >> 4) * 8;
            const int bi = (wc * 64 + i * 16 + (lane & 15)) * 32 + (lane >> 4) * 8;
            af0[i] = *(const bf16x8*)&A0[ai];
            af1[i] = *(const bf16x8*)&A1[ai];
            bf_[i] = *(const bf16x8*)&Bs[bi];
        }
        #pragma unroll
        for (int i = 0; i < 4; ++i)
            #pragma unroll
            for (int j = 0; j < 4; ++j) {
                acc0[i][j] = __builtin_amdgcn_mfma_f32_16x16x32_bf16(af0[i], bf_[j], acc0[i][j], 0, 0, 0);
                acc1[i][j] = __builtin_amdgcn_mfma_f32_16x16x32_bf16(af1[i], bf_[j], acc1[i][j], 0, 0, 0);
            }
        __syncthreads();
    }

    const int col0 = n0 + wc * 64 + (lane & 15);
    const int row0 = m0 + wr * 64 + (lane >> 4) * 4;
    #pragma unroll
    for (int i = 0; i < 4; ++i)
        #pragma unroll
        for (int j = 0; j < 4; ++j) {
            const int col = col0 + j * 16;
            #pragma unroll
            for (int r = 0; r < 4; ++r) {
                const int row = row0 + i * 16 + r;
                O[(size_t)row * Cdim + col]         = acc0[i][j][r];
                O[(size_t)(row + 128) * Cdim + col] = acc1[i][j][r];
            }
        }
}

// ---------- WKV: constant-coefficient linear recurrence, chunk-parallel ----------
// Vectorized x8: each thread owns 8 consecutive channels (16B loads/stores).
__global__ __launch_bounds__(256)
void wkv_pass1(const u16* __restrict__ Vb, const float* __restrict__ td,
               float* __restrict__ Sa)
{
    const int t     = blockIdx.x * 256 + threadIdx.x;   // 0..32767
    const int cg    = t & 127;
    const int chunk = (t >> 7) & (NCH - 1);
    const int b     = t >> 12;
    const int c0    = cg * 8;

    const float4 t0 = *(const float4*)&td[c0];
    const float4 t1 = *(const float4*)&td[c0 + 4];
    const float tdv[8] = {t0.x, t0.y, t0.z, t0.w, t1.x, t1.y, t1.z, t1.w};
    float lam[8], mu[8];
    #pragma unroll
    for (int j = 0; j < 8; ++j) {
        lam[j] = __expf(-fmaxf(tdv[j], 0.f));
        mu[j]  = __expf(fminf(tdv[j], 0.f));
    }

    float s[8] = {};
    size_t idx = ((size_t)(b * Tn + chunk * CLEN)) * Cdim + c0;
    for (int i = 0; i < CLEN; ++i, idx += Cdim) {
        const uint4 pv = *(const uint4*)&Vb[idx];
        const u32 w[4] = {pv.x, pv.y, pv.z, pv.w};
        #pragma unroll
        for (int q = 0; q < 4; ++q) {
            s[2*q]   = lam[2*q]   * s[2*q]   + mu[2*q]   * bf2f_lo(w[q]);
            s[2*q+1] = lam[2*q+1] * s[2*q+1] + mu[2*q+1] * bf2f_hi(w[q]);
        }
    }
    float* dst = &Sa[((size_t)b * NCH + chunk) * Cdim + c0];
    *(float4*)dst       = make_float4(s[0], s[1], s[2], s[3]);
    *(float4*)(dst + 4) = make_float4(s[4], s[5], s[6], s[7]);
}

__global__ __launch_bounds__(256)
void wkv_pass2(const u16* __restrict__ Vb, const u16* __restrict__ Rb,
               const float* __restrict__ td, const float* __restrict__ tf,
               const float* __restrict__ Sa, u16* __restrict__ Y)
{
    const int t     = blockIdx.x * 256 + threadIdx.x;
    const int cg    = t & 127;
    const int chunk = (t >> 7) & (NCH - 1);
    const int b     = t >> 12;
    const int c0    = cg * 8;

    const float4 t0 = *(const float4*)&td[c0];
    const float4 t1 = *(const float4*)&td[c0 + 4];
    const float4 f0 = *(const float4*)&tf[c0];
    const float4 f1 = *(const float4*)&tf[c0 + 4];
    const float tdv[8] = {t0.x, t0.y, t0.z, t0.w, t1.x, t1.y, t1.z, t1.w};
    const float tfv[8] = {f0.x, f0.y, f0.z, f0.w, f1.x, f1.y, f1.z, f1.w};

    float lam[8], mu[8], e1[8], e2[8], lamL[8], Sb[8];
    #pragma unroll
    for (int j = 0; j < 8; ++j) {
        const float mx = fmaxf(tdv[j], 0.f);
        lam[j]  = __expf(-mx);
        mu[j]   = __expf(fminf(tdv[j], 0.f));
        e1[j]   = __expf(-fmaxf(tfv[j], 0.f));
        e2[j]   = __expf(fminf(tfv[j], 0.f));
        lamL[j] = __expf(-(float)CLEN * mx);
        Sb[j]   = (fabsf(1.f - lam[j]) < 1e-9f) ? mu[j] * (float)CLEN
                                                : mu[j] * (1.f - lamL[j]) / (1.f - lam[j]);
    }

    float aa[8] = {}, bb[8] = {};
    for (int jj = 0; jj < chunk; ++jj) {            // chunk is wave-uniform
        const float* sp = &Sa[((size_t)b * NCH + jj) * Cdim + c0];
        const float4 s0 = *(const float4*)sp;
        const float4 s1 = *(const float4*)(sp + 4);
        const float sv[8] = {s0.x, s0.y, s0.z, s0.w, s1.x, s1.y, s1.z, s1.w};
        #pragma unroll
        for (int j = 0; j < 8; ++j) {
            aa[j] = lamL[j] * aa[j] + sv[j];
            bb[j] = lamL[j] * bb[j] + Sb[j];
        }
    }

    size_t idx = ((size_t)(b * Tn + chunk * CLEN)) * Cdim + c0;
    for (int i = 0; i < CLEN; ++i, idx += Cdim) {
        const uint4 pv = *(const uint4*)&Vb[idx];
        const uint4 pr = *(const uint4*)&Rb[idx];
        const u32 vw[4] = {pv.x, pv.y, pv.z, pv.w};
        const u32 rw[4] = {pr.x, pr.y, pr.z, pr.w};
        u32 ow[4];
        #pragma unroll
        for (int q = 0; q < 4; ++q) {
            const int j0 = 2 * q, j1 = 2 * q + 1;
            const float v0 = bf2f_lo(vw[q]), v1 = bf2f_hi(vw[q]);
            const float r0 = bf2f_lo(rw[q]), r1 = bf2f_hi(rw[q]);
            const float k0 = (e1[j0] * aa[j0] + e2[j0] * v0) / (e1[j0] * bb[j0] + e2[j0] + 1e-6f);
            const float k1 = (e1[j1] * aa[j1] + e2[j1] * v1) / (e1[j1] * bb[j1] + e2[j1] + 1e-6f);
            ow[q] = (u32)f2bf(r0 * k0) | ((u32)f2bf(r1 * k1) << 16);
            aa[j0] = lam[j0] * aa[j0] + mu[j0] * v0;
            aa[j1] = lam[j1] * aa[j1] + mu[j1] * v1;
            bb[j0] = lam[j0] * bb[j0] + mu[j0];
            bb[j1] = lam[j1] * bb[j1] + mu[j1];
        }
        *(uint4*)&Y[idx] = make_uint4(ow[0], ow[1], ow[2], ow[3]);
    }
}

extern "C" void kernel_launch(void* const* d_in, const int* in_sizes, int n_in,
                              void* d_out, int out_size, void* d_ws, size_t ws_size,
                              hipStream_t stream)
{
    // inputs: x, time_decay, time_first, key_w(dead), value_w, recep_w, out_w
    const float* x       = (const float*)d_in[0];
    const float* td      = (const float*)d_in[1];
    const float* tf      = (const float*)d_in[2];
    const float* value_w = (const float*)d_in[4];
    const float* recep_w = (const float*)d_in[5];
    const float* out_w   = (const float*)d_in[6];
    float* out = (float*)d_out;

    char* ws = (char*)d_ws;
    const size_t MB = 1024 * 1024;
    u16*   Xb = (u16*)(ws);               // 32 MB; reused as Yb after dual GEMM
    u16*   Vb = (u16*)(ws + 32 * MB);     // 32 MB
    u16*   Rb = (u16*)(ws + 64 * MB);     // 32 MB
    u16*   Wv = (u16*)(ws + 96 * MB);     //  2 MB
    u16*   Wr = (u16*)(ws + 98 * MB);     //  2 MB
    u16*   Wo = (u16*)(ws + 100 * MB);    //  2 MB
    float* Sa = (float*)(ws + 102 * MB);  //  1 MB [8][32][1024]
    u16*   Yb = Xb;                       // alias: Xb dead after dual GEMM

    cast_all<<<XB + 3 * WB, 256, 0, stream>>>(x, value_w, recep_w, out_w, Xb, Wv, Wr, Wo);

    dim3 ggrid(Cdim / 128, Mrows / 128);  // (8, 128) -> 1024 blocks
    gemm_dual<<<ggrid, 256, 0, stream>>>(Xb, Wv, Wr, Vb, Rb);

    const int nScan = Bn * NCH * (Cdim / 8);   // 32768 threads
    wkv_pass1<<<nScan / 256, 256, 0, stream>>>(Vb, td, Sa);
    wkv_pass2<<<nScan / 256, 256, 0, stream>>>(Vb, Rb, td, tf, Sa, Yb);

    gemm_single2<<<512, 256, 0, stream>>>(Yb, Wo, out);
}